// Round 9
// baseline (103.851 us; speedup 1.0000x reference)
//
#include <hip/hip_runtime.h>
#include <hip/hip_bf16.h>
#include <stdint.h>

// Problem constants: B=4, N=4096, C=1024, H=16, d=64
typedef __attribute__((ext_vector_type(8))) short bf16x8;
typedef __attribute__((ext_vector_type(4))) short bf16x4;
typedef __attribute__((ext_vector_type(4))) float f32x4;
typedef __attribute__((ext_vector_type(4))) int   i32x4;

static __device__ __forceinline__ short f2bs(float f) {
  __hip_bfloat16 h = __float2bfloat16(f);
  return __builtin_bit_cast(short, h);
}

__device__ __forceinline__ void gload_lds16(const void* g, void* l) {
  auto* gp = reinterpret_cast<__attribute__((address_space(1))) uint32_t*>((uintptr_t)g);
  auto* lp = reinterpret_cast<__attribute__((address_space(3))) uint32_t*>((uintptr_t)l);
  __builtin_amdgcn_global_load_lds(gp, lp, 16, 0, 0);
}

// ---------------------------------------------------------------------------
// Kernel 1: per-token head-mix attention + fused W fp32->bf16 (unchanged).
// ---------------------------------------------------------------------------
__global__ __launch_bounds__(256) void attn_kernel(
    const float* __restrict__ x, const float* __restrict__ y,
    __hip_bfloat16* __restrict__ A,
    const float* __restrict__ W, __hip_bfloat16* __restrict__ Wb)
{
  if (blockIdx.x < 1024) {
    const int i = (blockIdx.x * 256 + threadIdx.x) * 4;
    const float4 v = *(const float4*)(W + i);
    Wb[i + 0] = __float2bfloat16(v.x);
    Wb[i + 1] = __float2bfloat16(v.y);
    Wb[i + 2] = __float2bfloat16(v.z);
    Wb[i + 3] = __float2bfloat16(v.w);
  }

  const int wid  = threadIdx.x >> 6;
  const int lane = threadIdx.x & 63;
  const int tok  = blockIdx.x * 4 + wid;        // 0..16383
  const int b    = tok >> 12;
  const int n    = tok & 4095;

  const float* xr = x + (size_t)tok * 1024;
  const float* yr = y + (size_t)tok * 1024;

  const int c  = lane & 15;
  const int qq = lane >> 4;

  const int fbase = c * 64 + qq * 8;
  bf16x8 yf[2], xf[2];
  #pragma unroll
  for (int kk = 0; kk < 2; ++kk) {
    const float4 a0 = *(const float4*)(yr + fbase + kk * 32);
    const float4 a1 = *(const float4*)(yr + fbase + kk * 32 + 4);
    const float4 b0 = *(const float4*)(xr + fbase + kk * 32);
    const float4 b1 = *(const float4*)(xr + fbase + kk * 32 + 4);
    yf[kk] = bf16x8{f2bs(a0.x), f2bs(a0.y), f2bs(a0.z), f2bs(a0.w),
                    f2bs(a1.x), f2bs(a1.y), f2bs(a1.z), f2bs(a1.w)};
    xf[kk] = bf16x8{f2bs(b0.x), f2bs(b0.y), f2bs(b0.z), f2bs(b0.w),
                    f2bs(b1.x), f2bs(b1.y), f2bs(b1.z), f2bs(b1.w)};
  }

  f32x4 acc = {0.f, 0.f, 0.f, 0.f};
  acc = __builtin_amdgcn_mfma_f32_16x16x32_bf16(yf[0], xf[0], acc, 0, 0, 0);
  acc = __builtin_amdgcn_mfma_f32_16x16x32_bf16(yf[1], xf[1], acc, 0, 0, 0);

  float sc[4];
  #pragma unroll
  for (int r = 0; r < 4; ++r) sc[r] = acc[r] * 0.125f;
  float mx = fmaxf(fmaxf(sc[0], sc[1]), fmaxf(sc[2], sc[3]));
  mx = fmaxf(mx, __shfl_xor(mx, 16));
  mx = fmaxf(mx, __shfl_xor(mx, 32));
  float e[4];
  #pragma unroll
  for (int r = 0; r < 4; ++r) e[r] = __expf(sc[r] - mx);
  float sm = (e[0] + e[1]) + (e[2] + e[3]);
  sm += __shfl_xor(sm, 16);
  sm += __shfl_xor(sm, 32);
  const float inv = 1.0f / sm;
  float p[4];
  #pragma unroll
  for (int r = 0; r < 4; ++r) p[r] = e[r] * inv;

  f32x4 o[4];
  #pragma unroll
  for (int q = 0; q < 4; ++q) o[q] = f32x4{0.f, 0.f, 0.f, 0.f};

#if __has_builtin(__builtin_amdgcn_mfma_f32_16x16x16bf16_1k)
  const bf16x4 pa = {f2bs(p[0]), f2bs(p[1]), f2bs(p[2]), f2bs(p[3])};
  #pragma unroll
  for (int q = 0; q < 4; ++q) {
    bf16x4 bq;
    #pragma unroll
    for (int j = 0; j < 4; ++j)
      bq[j] = f2bs(yr[(qq * 4 + j) * 64 + q * 16 + c]);
    o[q] = __builtin_amdgcn_mfma_f32_16x16x16bf16_1k(pa, bq, o[q], 0, 0, 0);
  }
#else
  const int u0 = ((int)(unsigned short)f2bs(p[1]) << 16) | (unsigned short)f2bs(p[0]);
  const int u1 = ((int)(unsigned short)f2bs(p[3]) << 16) | (unsigned short)f2bs(p[2]);
  const int s0 = c + 32 * qq;
  int a0 = __shfl(u0, s0), a1 = __shfl(u1, s0);
  int a2 = __shfl(u0, s0 + 16), a3 = __shfl(u1, s0 + 16);
  const bool valid = (qq < 2);
  if (!valid) { a0 = 0; a1 = 0; a2 = 0; a3 = 0; }
  const bf16x8 a8 = __builtin_bit_cast(bf16x8, i32x4{a0, a1, a2, a3});
  #pragma unroll
  for (int q = 0; q < 4; ++q) {
    bf16x8 b8;
    #pragma unroll
    for (int j = 0; j < 8; ++j) {
      const int g = (qq * 8 + j) & 15;
      const float v = yr[g * 64 + q * 16 + c];
      b8[j] = valid ? f2bs(v) : (short)0;
    }
    o[q] = __builtin_amdgcn_mfma_f32_16x16x32_bf16(a8, b8, o[q], 0, 0, 0);
  }
#endif

  const size_t base = ((size_t)b * 4096 + (n >> 4)) * 1024 + ((n & 15) << 6) + c;
  #pragma unroll
  for (int q = 0; q < 4; ++q)
    #pragma unroll
    for (int r = 0; r < 4; ++r) {
      const int h = qq * 4 + r;
      A[base + (size_t)h * 262144 + q * 16] = __float2bfloat16(o[q][r]);
    }
}

// ---------------------------------------------------------------------------
// Kernel 2: out[M,Nn] = A[M,K] * Bw[Nn,K]^T + bias, fp32 out.
// NO per-step staging: W-panel (64 cols x 1024 K = 128 KB) staged in LDS
// ONCE (swizzled); A-fragments load DIRECTLY global->VGPR (no LDS, no
// barriers in the K-loop). 512 thr = 8 waves, each wave: 2 strips of 64
// rows x 64 cols (acc[4][4]); register double-buffer, prefetch distance 2
// K-steps. Grid 256 (1 block/CU): xcd = mchunk>>1 so each XCD's L2 holds
// 2 A-chunks (4 MB) reused by 16 N-panels.
// ---------------------------------------------------------------------------
__global__ __launch_bounds__(512, 2) void gemm_stream(
    const __hip_bfloat16* __restrict__ A,   // [M=16384, K=1024] bf16 row-major
    const __hip_bfloat16* __restrict__ Bw,  // [Nn=1024, K=1024] bf16 (= W^T)
    const float* __restrict__ bias,         // [Nn]
    float* __restrict__ C)                  // [M, Nn] fp32
{
  __shared__ char ldsW[131072];             // [64 n][2048 B], 16B-slot swizzled

  const int tid  = threadIdx.x;             // 0..511
  const int lane = tid & 63;
  const int wid  = tid >> 6;                // 8 waves, one 128-row group each

  // grid 256: xcd = bid&7; mchunk = (bid&7)*2 + ((bid>>3)&1); npanel = bid>>4
  const int bid    = blockIdx.x;
  const int mchunk = ((bid & 7) << 1) | ((bid >> 3) & 1);  // 0..15 (1024 rows)
  const int npanel = bid >> 4;                             // 0..15 (64 cols)
  const int nBase  = npanel * 64;
  const int mWave  = mchunk * 1024 + wid * 128;            // this wave's 128 rows

  // ---- stage W-panel once: 16 x gload_lds (linear dest, pre-swizzled src) --
  // LDS layout: row n (0..63) at n*2048; 16B slot s holds logical slot s^(n&7)
  {
    const int nrow = tid >> 7;              // 0..3 within each 4-row chunk
    const int sl   = tid & 127;             // slot 0..127
    #pragma unroll
    for (int cc = 0; cc < 16; ++cc) {
      const int row = cc * 4 + nrow;
      gload_lds16((const char*)Bw + (size_t)(nBase + row) * 2048
                                  + ((sl ^ (row & 7)) << 4),
                  ldsW + cc * 8192 + tid * 16);
    }
    __syncthreads();
  }

  const int fr = lane & 15;                 // fragment row/col
  const int kq = lane >> 4;                 // k-quad (0..3)

  // B ds_read addressing: frag nf, kstep ks -> row = nf*16+fr,
  // phys slot = ((ks<<2)|kq) ^ (row&7); split: low2 = kq^(row&3... (row&7)&3),
  // high = ks ^ ((row&7)>>2). Precompute per-lane bases.
  int bBase[4], bXs[4];
  #pragma unroll
  for (int nf = 0; nf < 4; ++nf) {
    const int row = nf * 16 + fr;
    const int h   = row & 7;
    bBase[nf] = row * 2048 + ((kq ^ (h & 3)) << 4);
    bXs[nf]   = (h >> 2);                   // XORs into ks
  }

  // A global addressing: strip s2, frag mf, kstep ks ->
  // byte (mWave + s2*64 + mf*16 + fr)*2048 + ks*64 + kq*16
  const float* __restrict__ biasp = bias;

  #pragma unroll 1
  for (int s2 = 0; s2 < 2; ++s2) {
    const int m0 = mWave + s2 * 64;
    const char* aRow[4];
    #pragma unroll
    for (int mf = 0; mf < 4; ++mf)
      aRow[mf] = (const char*)A + (size_t)(m0 + mf * 16 + fr) * 2048 + kq * 16;

    f32x4 acc[4][4];
    #pragma unroll
    for (int m = 0; m < 4; ++m)
      #pragma unroll
      for (int n = 0; n < 4; ++n) acc[m][n] = f32x4{0.f, 0.f, 0.f, 0.f};

    bf16x8 A0[4], A1[4], B0[4], B1[4];

    // prologue: load ksteps 0 and 1
    #pragma unroll
    for (int mf = 0; mf < 4; ++mf) A0[mf] = *(const bf16x8*)(aRow[mf]);
    #pragma unroll
    for (int nf = 0; nf < 4; ++nf)
      B0[nf] = *(const bf16x8*)(ldsW + bBase[nf] + (((0 ^ bXs[nf])) << 6));
    #pragma unroll
    for (int mf = 0; mf < 4; ++mf) A1[mf] = *(const bf16x8*)(aRow[mf] + 64);
    #pragma unroll
    for (int nf = 0; nf < 4; ++nf)
      B1[nf] = *(const bf16x8*)(ldsW + bBase[nf] + (((1 ^ bXs[nf])) << 6));

    // main: 2-step bodies; mfma(cur) then refill cur with ks+2
    for (int ks = 0; ks < 32; ks += 2) {
      {
        #pragma unroll
        for (int m = 0; m < 4; ++m)
          #pragma unroll
          for (int n = 0; n < 4; ++n)
            acc[m][n] = __builtin_amdgcn_mfma_f32_16x16x32_bf16(A0[m], B0[n], acc[m][n], 0, 0, 0);
        const int kp = (ks + 2 < 32) ? (ks + 2) : 0;
        #pragma unroll
        for (int mf = 0; mf < 4; ++mf)
          A0[mf] = *(const bf16x8*)(aRow[mf] + kp * 64);
        #pragma unroll
        for (int nf = 0; nf < 4; ++nf)
          B0[nf] = *(const bf16x8*)(ldsW + bBase[nf] + ((kp ^ bXs[nf]) << 6));
      }
      {
        #pragma unroll
        for (int m = 0; m < 4; ++m)
          #pragma unroll
          for (int n = 0; n < 4; ++n)
            acc[m][n] = __builtin_amdgcn_mfma_f32_16x16x32_bf16(A1[m], B1[n], acc[m][n], 0, 0, 0);
        const int kp = (ks + 3 < 32) ? (ks + 3) : 1;
        #pragma unroll
        for (int mf = 0; mf < 4; ++mf)
          A1[mf] = *(const bf16x8*)(aRow[mf] + kp * 64);
        #pragma unroll
        for (int nf = 0; nf < 4; ++nf)
          B1[nf] = *(const bf16x8*)(ldsW + bBase[nf] + ((kp ^ bXs[nf]) << 6));
      }
    }

    // strip epilogue: C/D layout col=lane&15, row=(lane>>4)*4+reg.
    // Strip 0's stores overlap strip 1's K-loop (no barrier between).
    #pragma unroll
    for (int n = 0; n < 4; ++n) {
      const int col = nBase + n * 16 + fr;
      const float bv = biasp[col];
      #pragma unroll
      for (int m = 0; m < 4; ++m) {
        const int row0 = m0 + m * 16 + kq * 4;
        #pragma unroll
        for (int r = 0; r < 4; ++r)
          C[(size_t)(row0 + r) * 1024 + col] = acc[m][n][r] + bv;
      }
    }
  }
}

extern "C" void kernel_launch(void* const* d_in, const int* in_sizes, int n_in,
                              void* d_out, int out_size, void* d_ws, size_t ws_size,
                              hipStream_t stream) {
  const float* x    = (const float*)d_in[0];
  const float* y    = (const float*)d_in[1];
  const float* W    = (const float*)d_in[2];
  const float* bias = (const float*)d_in[3];
  float* out = (float*)d_out;

  // Workspace: A (16384x1024 bf16 = 32 MB) + Wbf16 (2 MB)
  __hip_bfloat16* Abuf = (__hip_bfloat16*)d_ws;
  __hip_bfloat16* Wbuf = (__hip_bfloat16*)((char*)d_ws + (size_t)16384 * 1024 * 2);

  attn_kernel<<<4096, 256, 0, stream>>>(x, y, Abuf, W, Wbuf);
  gemm_stream<<<256, 512, 0, stream>>>(Abuf, Wbuf, bias, out);
}

// Round 10
// 86.047 us; speedup vs baseline: 1.2069x; 1.2069x over previous
//
#include <hip/hip_runtime.h>
#include <hip/hip_bf16.h>
#include <stdint.h>

// Problem constants: B=4, N=4096, C=1024, H=16, d=64
typedef __attribute__((ext_vector_type(8))) short bf16x8;
typedef __attribute__((ext_vector_type(4))) short bf16x4;
typedef __attribute__((ext_vector_type(4))) float f32x4;
typedef __attribute__((ext_vector_type(4))) int   i32x4;

static __device__ __forceinline__ short f2bs(float f) {
  __hip_bfloat16 h = __float2bfloat16(f);
  return __builtin_bit_cast(short, h);
}

__device__ __forceinline__ void gload_lds16(const void* g, void* l) {
  auto* gp = reinterpret_cast<__attribute__((address_space(1))) uint32_t*>((uintptr_t)g);
  auto* lp = reinterpret_cast<__attribute__((address_space(3))) uint32_t*>((uintptr_t)l);
  __builtin_amdgcn_global_load_lds(gp, lp, 16, 0, 0);
}

// ---------------------------------------------------------------------------
// Kernel 1: per-token head-mix attention + fused W fp32->bf16 (unchanged).
// ---------------------------------------------------------------------------
__global__ __launch_bounds__(256) void attn_kernel(
    const float* __restrict__ x, const float* __restrict__ y,
    __hip_bfloat16* __restrict__ A,
    const float* __restrict__ W, __hip_bfloat16* __restrict__ Wb)
{
  if (blockIdx.x < 1024) {
    const int i = (blockIdx.x * 256 + threadIdx.x) * 4;
    const float4 v = *(const float4*)(W + i);
    Wb[i + 0] = __float2bfloat16(v.x);
    Wb[i + 1] = __float2bfloat16(v.y);
    Wb[i + 2] = __float2bfloat16(v.z);
    Wb[i + 3] = __float2bfloat16(v.w);
  }

  const int wid  = threadIdx.x >> 6;
  const int lane = threadIdx.x & 63;
  const int tok  = blockIdx.x * 4 + wid;        // 0..16383
  const int b    = tok >> 12;
  const int n    = tok & 4095;

  const float* xr = x + (size_t)tok * 1024;
  const float* yr = y + (size_t)tok * 1024;

  const int c  = lane & 15;
  const int qq = lane >> 4;

  const int fbase = c * 64 + qq * 8;
  bf16x8 yf[2], xf[2];
  #pragma unroll
  for (int kk = 0; kk < 2; ++kk) {
    const float4 a0 = *(const float4*)(yr + fbase + kk * 32);
    const float4 a1 = *(const float4*)(yr + fbase + kk * 32 + 4);
    const float4 b0 = *(const float4*)(xr + fbase + kk * 32);
    const float4 b1 = *(const float4*)(xr + fbase + kk * 32 + 4);
    yf[kk] = bf16x8{f2bs(a0.x), f2bs(a0.y), f2bs(a0.z), f2bs(a0.w),
                    f2bs(a1.x), f2bs(a1.y), f2bs(a1.z), f2bs(a1.w)};
    xf[kk] = bf16x8{f2bs(b0.x), f2bs(b0.y), f2bs(b0.z), f2bs(b0.w),
                    f2bs(b1.x), f2bs(b1.y), f2bs(b1.z), f2bs(b1.w)};
  }

  f32x4 acc = {0.f, 0.f, 0.f, 0.f};
  acc = __builtin_amdgcn_mfma_f32_16x16x32_bf16(yf[0], xf[0], acc, 0, 0, 0);
  acc = __builtin_amdgcn_mfma_f32_16x16x32_bf16(yf[1], xf[1], acc, 0, 0, 0);

  float sc[4];
  #pragma unroll
  for (int r = 0; r < 4; ++r) sc[r] = acc[r] * 0.125f;
  float mx = fmaxf(fmaxf(sc[0], sc[1]), fmaxf(sc[2], sc[3]));
  mx = fmaxf(mx, __shfl_xor(mx, 16));
  mx = fmaxf(mx, __shfl_xor(mx, 32));
  float e[4];
  #pragma unroll
  for (int r = 0; r < 4; ++r) e[r] = __expf(sc[r] - mx);
  float sm = (e[0] + e[1]) + (e[2] + e[3]);
  sm += __shfl_xor(sm, 16);
  sm += __shfl_xor(sm, 32);
  const float inv = 1.0f / sm;
  float p[4];
  #pragma unroll
  for (int r = 0; r < 4; ++r) p[r] = e[r] * inv;

  f32x4 o[4];
  #pragma unroll
  for (int q = 0; q < 4; ++q) o[q] = f32x4{0.f, 0.f, 0.f, 0.f};

#if __has_builtin(__builtin_amdgcn_mfma_f32_16x16x16bf16_1k)
  const bf16x4 pa = {f2bs(p[0]), f2bs(p[1]), f2bs(p[2]), f2bs(p[3])};
  #pragma unroll
  for (int q = 0; q < 4; ++q) {
    bf16x4 bq;
    #pragma unroll
    for (int j = 0; j < 4; ++j)
      bq[j] = f2bs(yr[(qq * 4 + j) * 64 + q * 16 + c]);
    o[q] = __builtin_amdgcn_mfma_f32_16x16x16bf16_1k(pa, bq, o[q], 0, 0, 0);
  }
#else
  const int u0 = ((int)(unsigned short)f2bs(p[1]) << 16) | (unsigned short)f2bs(p[0]);
  const int u1 = ((int)(unsigned short)f2bs(p[3]) << 16) | (unsigned short)f2bs(p[2]);
  const int s0 = c + 32 * qq;
  int a0 = __shfl(u0, s0), a1 = __shfl(u1, s0);
  int a2 = __shfl(u0, s0 + 16), a3 = __shfl(u1, s0 + 16);
  const bool valid = (qq < 2);
  if (!valid) { a0 = 0; a1 = 0; a2 = 0; a3 = 0; }
  const bf16x8 a8 = __builtin_bit_cast(bf16x8, i32x4{a0, a1, a2, a3});
  #pragma unroll
  for (int q = 0; q < 4; ++q) {
    bf16x8 b8;
    #pragma unroll
    for (int j = 0; j < 8; ++j) {
      const int g = (qq * 8 + j) & 15;
      const float v = yr[g * 64 + q * 16 + c];
      b8[j] = valid ? f2bs(v) : (short)0;
    }
    o[q] = __builtin_amdgcn_mfma_f32_16x16x32_bf16(a8, b8, o[q], 0, 0, 0);
  }
#endif

  const size_t base = ((size_t)b * 4096 + (n >> 4)) * 1024 + ((n & 15) << 6) + c;
  #pragma unroll
  for (int q = 0; q < 4; ++q)
    #pragma unroll
    for (int r = 0; r < 4; ++r) {
      const int h = qq * 4 + r;
      A[base + (size_t)h * 262144 + q * 16] = __float2bfloat16(o[q][r]);
    }
}

// ---------------------------------------------------------------------------
// Kernel 2: out[M,Nn] = A[M,K] * Bw[Nn,K]^T + bias, fp32 out.
// R7 geometry (BM=256,BN=128,BK=32, 4 waves, wave 128x64, ring-3 LDS 72KB,
// 2 blocks/CU) + REGISTER-LEVEL DOUBLE BUFFER: body s issues the 12 ds_reads
// for step s+1 BEFORE MFMA(s) (no wait between) so LDS-pipe work (~1152
// cyc/CU/step) drains UNDER the MFMA section (~1242 cyc) instead of
// serializing with it. Per body: VM6 (stage s+1 landed) -> LGKM0 (my reads(s)
// done) -> BAR -> STG(s+3 -> buf[s%3]) -> reads(s+1) -> MFMA(s) w/ setprio.
// vmcnt never drains in the loop. Ring-3 x parity-2 regs -> 6-unrolled loop.
// ---------------------------------------------------------------------------
#define FENCE asm volatile("" ::: "memory")
#define BAR   __builtin_amdgcn_s_barrier()
#define LGKM0 asm volatile("s_waitcnt lgkmcnt(0)" ::: "memory")
#define VM12  asm volatile("s_waitcnt vmcnt(12)" ::: "memory")
#define VM6   asm volatile("s_waitcnt vmcnt(6)" ::: "memory")
#define VM0   asm volatile("s_waitcnt vmcnt(0)" ::: "memory")
#define SP1   __builtin_amdgcn_s_setprio(1)
#define SP0   __builtin_amdgcn_s_setprio(0)

// stage K-step sp into ring buffer wb: A 16KB (4 bands) + B 8KB (2 bands)
#define STG(sp, wb) do {                                                  \
    const int ko_ = (sp) * 64;                                            \
    char* aD_ = ldsA + (wb) * 16384 + tid * 16;                           \
    char* bD_ = ldsB + (wb) * 8192  + tid * 16;                           \
    gload_lds16(aS0 + ko_, aD_);                                          \
    gload_lds16(aS1 + ko_, aD_ + 4096);                                   \
    gload_lds16(aS2 + ko_, aD_ + 8192);                                   \
    gload_lds16(aS3 + ko_, aD_ + 12288);                                  \
    gload_lds16(bS0 + ko_, bD_);                                          \
    gload_lds16(bS1 + ko_, bD_ + 4096);                                   \
  } while (0)

#define RD(RA, RB_, rb) do {                                              \
    _Pragma("unroll")                                                     \
    for (int mf = 0; mf < 8; ++mf)                                        \
      RA[mf] = *(const bf16x8*)(ldsA + (rb) * 16384 + aOff + mf * 1024);  \
    _Pragma("unroll")                                                     \
    for (int nf = 0; nf < 4; ++nf)                                        \
      RB_[nf] = *(const bf16x8*)(ldsB + (rb) * 8192 + bOff + nf * 1024);  \
  } while (0)

#define MM(MA, MB_) do {                                                  \
    SP1;                                                                  \
    _Pragma("unroll")                                                     \
    for (int m = 0; m < 8; ++m)                                           \
      _Pragma("unroll")                                                   \
      for (int n = 0; n < 4; ++n)                                         \
        acc[m][n] = __builtin_amdgcn_mfma_f32_16x16x32_bf16(MA[m], MB_[n], acc[m][n], 0, 0, 0); \
    SP0;                                                                  \
  } while (0)

// body s: gate, publish, stage s+3, read frags(s+1), MFMA frags(s)
#define BODY(S, RBUF, WBUF, RDA, RDB, MMA, MMB, GATE, DOSTG) do {         \
    GATE; LGKM0; FENCE; BAR; FENCE;                                       \
    if (DOSTG) STG((S) + 3, WBUF);                                        \
    RD(RDA, RDB, RBUF);                                                   \
    MM(MMA, MMB);                                                         \
  } while (0)

__global__ __launch_bounds__(256, 2) void gemm_pipe(
    const __hip_bfloat16* __restrict__ A,   // [M=16384, K=1024] bf16
    const __hip_bfloat16* __restrict__ Bw,  // [Nn=1024, K=1024] bf16 (= W^T)
    const float* __restrict__ bias,         // [Nn]
    float* __restrict__ C)                  // [M, Nn] fp32
{
  __shared__ char ldsA[3 * 16384];          // ring-3: [buf][256 rows][64B]
  __shared__ char ldsB[3 * 8192];           // ring-3: [buf][128 rows][64B]

  const int tid  = threadIdx.x;             // 0..255
  const int lane = tid & 63;
  const int wid  = tid >> 6;                // 4 waves: 2M x 2N
  const int wr   = wid >> 1;                // 0..1 (128 rows)
  const int wcN  = wid & 1;                 // 0..1 (64 cols)

  // Grid 512: xcd = bid&7 = mg%8 -> 4MB A-chunk pinned per XCD L2, reused 8x.
  const int bid   = blockIdx.x;
  const int mg    = (bid & 7) | (((bid >> 3) & 7) << 3);  // 0..63
  const int nt    = (bid >> 6) & 7;                       // 0..7
  const int mBase = mg * 256;
  const int nBase = nt * 128;

  // staging: linear LDS dest, pre-swizzled global source (2-way-free swizzle)
  const int srow = tid >> 2;                // 0..63 (row within 64-row band)
  const int lcb  = (((tid & 3) ^ ((srow >> 1) & 3)) << 4);
  const char* aS0 = (const char*)A  + (size_t)(mBase + srow)       * 2048 + lcb;
  const char* aS1 = (const char*)A  + (size_t)(mBase + 64 + srow)  * 2048 + lcb;
  const char* aS2 = (const char*)A  + (size_t)(mBase + 128 + srow) * 2048 + lcb;
  const char* aS3 = (const char*)A  + (size_t)(mBase + 192 + srow) * 2048 + lcb;
  const char* bS0 = (const char*)Bw + (size_t)(nBase + srow)       * 2048 + lcb;
  const char* bS1 = (const char*)Bw + (size_t)(nBase + 64 + srow)  * 2048 + lcb;

  // ds_read: row R, k-quad kq -> byte R*64 + (kq ^ ((R>>1)&3))*16
  const int fr = lane & 15;
  const int kq = lane >> 4;
  const int ofk  = ((kq ^ ((fr >> 1) & 3)) << 4);
  const int aOff = (wr * 128 + fr) * 64 + ofk;
  const int bOff = (wcN * 64  + fr) * 64 + ofk;

  f32x4 acc[8][4];
  #pragma unroll
  for (int m = 0; m < 8; ++m)
    #pragma unroll
    for (int n = 0; n < 4; ++n) acc[m][n] = f32x4{0.f, 0.f, 0.f, 0.f};

  bf16x8 A0[8], B0[4], A1[8], B1[4];        // parity-2 fragment sets

  // prologue: stage steps 0,1,2 (18 loads); prove stage(0); read frags(0)
  STG(0, 0); STG(1, 1); STG(2, 2);
  VM12; FENCE; BAR; FENCE;
  RD(A0, B0, 0);

  // bodies 0..29, 6-unrolled (ring-3 x parity-2); stage(s+3) while s+3<32
  for (int g = 0; g < 5; ++g) {
    const int s = g * 6;
    BODY(s + 0, 1, 0, A1, B1, A0, B0, VM6, true);
    BODY(s + 1, 2, 1, A0, B0, A1, B1, VM6, true);
    BODY(s + 2, 0, 2, A1, B1, A0, B0, VM6, true);
    BODY(s + 3, 1, 0, A0, B0, A1, B1, VM6, true);
    BODY(s + 4, 2, 1, A1, B1, A0, B0, VM6, true);
    BODY(s + 5, 0, 2, A0, B0, A1, B1, VM6, g < 4);
  }
  // body 30: gate VM0 (prove stage 31), read frags(31) from buf1, MFMA F0
  BODY(30, 1, 0, A1, B1, A0, B0, VM0, false);
  // body 31: MFMA F1 (compiler inserts the lgkm wait for A1/B1)
  MM(A1, B1);

  // epilogue: C/D layout col=lane&15, row=(lane>>4)*4+reg.
  #pragma unroll
  for (int n = 0; n < 4; ++n) {
    const int col = nBase + wcN * 64 + n * 16 + fr;
    const float bv = bias[col];
    #pragma unroll
    for (int m = 0; m < 8; ++m) {
      const int row0 = mBase + wr * 128 + m * 16 + kq * 4;
      #pragma unroll
      for (int r = 0; r < 4; ++r)
        C[(size_t)(row0 + r) * 1024 + col] = acc[m][n][r] + bv;
    }
  }
}

extern "C" void kernel_launch(void* const* d_in, const int* in_sizes, int n_in,
                              void* d_out, int out_size, void* d_ws, size_t ws_size,
                              hipStream_t stream) {
  const float* x    = (const float*)d_in[0];
  const float* y    = (const float*)d_in[1];
  const float* W    = (const float*)d_in[2];
  const float* bias = (const float*)d_in[3];
  float* out = (float*)d_out;

  // Workspace: A (16384x1024 bf16 = 32 MB) + Wbf16 (2 MB)
  __hip_bfloat16* Abuf = (__hip_bfloat16*)d_ws;
  __hip_bfloat16* Wbuf = (__hip_bfloat16*)((char*)d_ws + (size_t)16384 * 1024 * 2);

  attn_kernel<<<4096, 256, 0, stream>>>(x, y, Abuf, W, Wbuf);
  gemm_pipe<<<512, 256, 0, stream>>>(Abuf, Wbuf, bias, out);
}

// Round 11
// 81.438 us; speedup vs baseline: 1.2752x; 1.0566x over previous
//
#include <hip/hip_runtime.h>
#include <hip/hip_bf16.h>
#include <stdint.h>

// Problem constants: B=4, N=4096, C=1024, H=16, d=64
typedef __attribute__((ext_vector_type(8))) short bf16x8;
typedef __attribute__((ext_vector_type(4))) short bf16x4;
typedef __attribute__((ext_vector_type(4))) float f32x4;
typedef __attribute__((ext_vector_type(4))) int   i32x4;

static __device__ __forceinline__ short f2bs(float f) {
  __hip_bfloat16 h = __float2bfloat16(f);
  return __builtin_bit_cast(short, h);
}

__device__ __forceinline__ void gload_lds16(const void* g, void* l) {
  auto* gp = reinterpret_cast<__attribute__((address_space(1))) uint32_t*>((uintptr_t)g);
  auto* lp = reinterpret_cast<__attribute__((address_space(3))) uint32_t*>((uintptr_t)l);
  __builtin_amdgcn_global_load_lds(gp, lp, 16, 0, 0);
}

// ---------------------------------------------------------------------------
// Kernel 1: per-token head-mix attention + fused W fp32->bf16 (unchanged).
// ---------------------------------------------------------------------------
__global__ __launch_bounds__(256) void attn_kernel(
    const float* __restrict__ x, const float* __restrict__ y,
    __hip_bfloat16* __restrict__ A,
    const float* __restrict__ W, __hip_bfloat16* __restrict__ Wb)
{
  if (blockIdx.x < 1024) {
    const int i = (blockIdx.x * 256 + threadIdx.x) * 4;
    const float4 v = *(const float4*)(W + i);
    Wb[i + 0] = __float2bfloat16(v.x);
    Wb[i + 1] = __float2bfloat16(v.y);
    Wb[i + 2] = __float2bfloat16(v.z);
    Wb[i + 3] = __float2bfloat16(v.w);
  }

  const int wid  = threadIdx.x >> 6;
  const int lane = threadIdx.x & 63;
  const int tok  = blockIdx.x * 4 + wid;        // 0..16383
  const int b    = tok >> 12;
  const int n    = tok & 4095;

  const float* xr = x + (size_t)tok * 1024;
  const float* yr = y + (size_t)tok * 1024;

  const int c  = lane & 15;
  const int qq = lane >> 4;

  const int fbase = c * 64 + qq * 8;
  bf16x8 yf[2], xf[2];
  #pragma unroll
  for (int kk = 0; kk < 2; ++kk) {
    const float4 a0 = *(const float4*)(yr + fbase + kk * 32);
    const float4 a1 = *(const float4*)(yr + fbase + kk * 32 + 4);
    const float4 b0 = *(const float4*)(xr + fbase + kk * 32);
    const float4 b1 = *(const float4*)(xr + fbase + kk * 32 + 4);
    yf[kk] = bf16x8{f2bs(a0.x), f2bs(a0.y), f2bs(a0.z), f2bs(a0.w),
                    f2bs(a1.x), f2bs(a1.y), f2bs(a1.z), f2bs(a1.w)};
    xf[kk] = bf16x8{f2bs(b0.x), f2bs(b0.y), f2bs(b0.z), f2bs(b0.w),
                    f2bs(b1.x), f2bs(b1.y), f2bs(b1.z), f2bs(b1.w)};
  }

  f32x4 acc = {0.f, 0.f, 0.f, 0.f};
  acc = __builtin_amdgcn_mfma_f32_16x16x32_bf16(yf[0], xf[0], acc, 0, 0, 0);
  acc = __builtin_amdgcn_mfma_f32_16x16x32_bf16(yf[1], xf[1], acc, 0, 0, 0);

  float sc[4];
  #pragma unroll
  for (int r = 0; r < 4; ++r) sc[r] = acc[r] * 0.125f;
  float mx = fmaxf(fmaxf(sc[0], sc[1]), fmaxf(sc[2], sc[3]));
  mx = fmaxf(mx, __shfl_xor(mx, 16));
  mx = fmaxf(mx, __shfl_xor(mx, 32));
  float e[4];
  #pragma unroll
  for (int r = 0; r < 4; ++r) e[r] = __expf(sc[r] - mx);
  float sm = (e[0] + e[1]) + (e[2] + e[3]);
  sm += __shfl_xor(sm, 16);
  sm += __shfl_xor(sm, 32);
  const float inv = 1.0f / sm;
  float p[4];
  #pragma unroll
  for (int r = 0; r < 4; ++r) p[r] = e[r] * inv;

  f32x4 o[4];
  #pragma unroll
  for (int q = 0; q < 4; ++q) o[q] = f32x4{0.f, 0.f, 0.f, 0.f};

#if __has_builtin(__builtin_amdgcn_mfma_f32_16x16x16bf16_1k)
  const bf16x4 pa = {f2bs(p[0]), f2bs(p[1]), f2bs(p[2]), f2bs(p[3])};
  #pragma unroll
  for (int q = 0; q < 4; ++q) {
    bf16x4 bq;
    #pragma unroll
    for (int j = 0; j < 4; ++j)
      bq[j] = f2bs(yr[(qq * 4 + j) * 64 + q * 16 + c]);
    o[q] = __builtin_amdgcn_mfma_f32_16x16x16bf16_1k(pa, bq, o[q], 0, 0, 0);
  }
#else
  const int u0 = ((int)(unsigned short)f2bs(p[1]) << 16) | (unsigned short)f2bs(p[0]);
  const int u1 = ((int)(unsigned short)f2bs(p[3]) << 16) | (unsigned short)f2bs(p[2]);
  const int s0 = c + 32 * qq;
  int a0 = __shfl(u0, s0), a1 = __shfl(u1, s0);
  int a2 = __shfl(u0, s0 + 16), a3 = __shfl(u1, s0 + 16);
  const bool valid = (qq < 2);
  if (!valid) { a0 = 0; a1 = 0; a2 = 0; a3 = 0; }
  const bf16x8 a8 = __builtin_bit_cast(bf16x8, i32x4{a0, a1, a2, a3});
  #pragma unroll
  for (int q = 0; q < 4; ++q) {
    bf16x8 b8;
    #pragma unroll
    for (int j = 0; j < 8; ++j) {
      const int g = (qq * 8 + j) & 15;
      const float v = yr[g * 64 + q * 16 + c];
      b8[j] = valid ? f2bs(v) : (short)0;
    }
    o[q] = __builtin_amdgcn_mfma_f32_16x16x32_bf16(a8, b8, o[q], 0, 0, 0);
  }
#endif

  const size_t base = ((size_t)b * 4096 + (n >> 4)) * 1024 + ((n & 15) << 6) + c;
  #pragma unroll
  for (int q = 0; q < 4; ++q)
    #pragma unroll
    for (int r = 0; r < 4; ++r) {
      const int h = qq * 4 + r;
      A[base + (size_t)h * 262144 + q * 16] = __float2bfloat16(o[q][r]);
    }
}

// ---------------------------------------------------------------------------
// Kernel 2: WAVE-AUTONOMOUS GEMM  out[M,Nn] = A[M,K] * Bw[Nn,K]^T + bias.
// Block: 512 thr / 8 waves, covers 512 rows x 64 cols. B (W-panel) staged in
// shared LDS one K-half (64KB) at a time -> only 3 barriers total. A staged
// PER-WAVE into private ring-2 LDS (8 x 8KB): each wave self-times with
// vmcnt(4); stage(s+2) issued after lgkmcnt(0) proves this wave's reads of
// that buffer finished. No lockstep => waves drift; ds_read and MFMA pipes
// overlap across the 2 waves/SIMD. Both LDS layouts use the proven
// 0-conflict pattern: row*64B rows, slot = kq ^ ((row>>1)&3).
// Wave tile 64x64 (acc[4][4] = 64 VGPR). Grid 512 = [mgH:2][nt:4][xcd:3],
// mg%8 == xcd -> <=2MB A + 2MB W live per XCD L2.
// ---------------------------------------------------------------------------
#define FENCE asm volatile("" ::: "memory")
#define BAR   __builtin_amdgcn_s_barrier()
#define LGKM0 asm volatile("s_waitcnt lgkmcnt(0)" ::: "memory")
#define VM4   asm volatile("s_waitcnt vmcnt(4)" ::: "memory")
#define VM0   asm volatile("s_waitcnt vmcnt(0)" ::: "memory")
#define SP1   __builtin_amdgcn_s_setprio(1)
#define SP0   __builtin_amdgcn_s_setprio(0)

__global__ __launch_bounds__(512, 2) void gemm_wp(
    const __hip_bfloat16* __restrict__ A,   // [M=16384, K=1024] bf16
    const __hip_bfloat16* __restrict__ Bw,  // [Nn=1024, K=1024] bf16 (= W^T)
    const float* __restrict__ bias,         // [Nn]
    float* __restrict__ C)                  // [M, Nn] fp32
{
  __shared__ char ldsB_[65536];  // [ksl 16][64 rows][64B] one K-half, swizzled
  __shared__ char ldsA_[65536];  // per-wave: [wave 8][buf 2][64 rows][64B]

  const int tid  = threadIdx.x;             // 0..511
  const int lane = tid & 63;
  const int wid  = tid >> 6;                // 8 waves, 64 rows each

  // grid decode: [mgH:2][nt:4][xcd:3]; mg%8 == xcd
  const int bid   = blockIdx.x;             // 0..511
  const int xcd   = bid & 7;
  const int nt    = (bid >> 3) & 15;
  const int mgH   = bid >> 7;               // 0..3
  const int mg    = (mgH << 3) | xcd;       // 0..31
  const int mBase = mg * 512;
  const int nBase = nt * 64;
  const int mWave = mBase + wid * 64;

  // ---- A staging (per-wave, 4 gloads of 1KB per step) ----
  // gload j covers rows j*16 + lane/4, phys slot lane&3; logical kq at phys
  // slot s for row r is s ^ ((r>>1)&3)  [proven 0-conflict pattern]
  const int arow = lane >> 2;               // 0..15 within 16-row group
  const char* aS0;
  {
    const int sl = lane & 3;
    aS0 = (const char*)A + (size_t)(mWave + arow) * 2048
        + ((sl ^ ((arow >> 1) & 3)) << 4);
  }
  // row-group j adds j*16 rows: xor term (r>>1)&3 is invariant under +16? r=j*16+arow
  // -> (r>>1)&3 = ((j*16+arow)>>1)&3 = (j*8 + (arow>>1))&3 = (arow>>1)&3  (j*8%4==0) OK
  char* aD = ldsA_ + wid * 8192 + lane * 16;

  // ---- B staging (whole block, 8 gloads of 8KB per K-half) ----
  // dest linear j*8192 + tid*16 -> ksl = j*2 + (tid>>8), row = (tid>>2)&63,
  // slot = tid&3; src slot logical = slot ^ ((row>>1)&3)
  const char* bS;
  {
    const int rowb = (tid >> 2) & 63;
    const int sl   = tid & 3;
    bS = (const char*)Bw + (size_t)(nBase + rowb) * 2048 + ((tid >> 8) << 6)
       + ((sl ^ ((rowb >> 1) & 3)) << 4);
  }

  // ---- ds_read geometry (shared by A and B): fr rows, kq k-quad ----
  const int fr = lane & 15;
  const int kq = lane >> 4;
  const int rdOff = fr * 64 + ((kq ^ ((fr >> 1) & 3)) << 4);
  const char* aRd = ldsA_ + wid * 8192 + rdOff;
  const char* bRd = ldsB_ + rdOff;

  f32x4 acc[4][4];
  #pragma unroll
  for (int m = 0; m < 4; ++m)
    #pragma unroll
    for (int n = 0; n < 4; ++n) acc[m][n] = f32x4{0.f, 0.f, 0.f, 0.f};

  // stage A K-step sp into ring buf (sp&1)
  auto STG_A = [&](int sp) {
    const char* s = aS0 + sp * 64;
    char* d = aD + ((sp & 1) << 12);
    gload_lds16(s,                       d);
    gload_lds16(s + 16 * 2048,           d + 1024);
    gload_lds16(s + 32 * 2048,           d + 2048);
    gload_lds16(s + 48 * 2048,           d + 3072);
  };

  // one K-step body (self-timed, no barrier)
  auto BODY = [&](int s, bool stg, bool last) {
    if (last) { VM0; } else { VM4; }        // A(s) landed (in-order drain)
    FENCE;
    const int ksl = s & 15;
    const char* aB = aRd + ((s & 1) << 12);
    const char* bB = bRd + (ksl << 12);
    bf16x8 Af[4], Bf[4];
    #pragma unroll
    for (int nf = 0; nf < 4; ++nf) Bf[nf] = *(const bf16x8*)(bB + nf * 1024);
    #pragma unroll
    for (int mf = 0; mf < 4; ++mf) Af[mf] = *(const bf16x8*)(aB + mf * 1024);
    LGKM0;                                   // my reads done -> buf reusable
    if (stg) STG_A(s + 2);                   // overwrite the buf just read
    SP1;
    #pragma unroll
    for (int m = 0; m < 4; ++m)
      #pragma unroll
      for (int n = 0; n < 4; ++n)
        acc[m][n] = __builtin_amdgcn_mfma_f32_16x16x32_bf16(Af[m], Bf[n], acc[m][n], 0, 0, 0);
    SP0;
  };

  // ---- prologue: B half-0 (8 gloads), A steps 0,1; prove B0+A0 ----
  #pragma unroll
  for (int j = 0; j < 8; ++j)
    gload_lds16(bS + j * 128, ldsB_ + j * 8192 + tid * 16);
  STG_A(0); STG_A(1);
  VM4; FENCE; BAR; FENCE;                   // leaves A(1) in flight

  // ---- K-half 0: steps 0..15 (all stage; A(17) issued at s=15) ----
  for (int s = 0; s < 16; ++s) BODY(s, true, false);

  // ---- swap B to half-1 (the only mid-kernel barriers) ----
  FENCE; BAR; FENCE;                        // all waves done reading B0
  #pragma unroll
  for (int j = 0; j < 8; ++j)
    gload_lds16(bS + 1024 + j * 128, ldsB_ + j * 8192 + tid * 16);
  VM4; FENCE; BAR; FENCE;                   // B1 landed (leaves A(17))

  // ---- K-half 1: steps 16..31 ----
  for (int s = 16; s < 30; ++s) BODY(s, true, false);
  BODY(30, false, false);
  BODY(31, false, true);

  // ---- epilogue (per-wave, no barrier) ----
  #pragma unroll
  for (int nf = 0; nf < 4; ++nf) {
    const int col = nBase + nf * 16 + fr;
    const float bv = bias[col];
    #pragma unroll
    for (int mf = 0; mf < 4; ++mf) {
      const int row0 = mWave + mf * 16 + kq * 4;
      #pragma unroll
      for (int r = 0; r < 4; ++r)
        C[(size_t)(row0 + r) * 1024 + col] = acc[mf][nf][r] + bv;
    }
  }
}

extern "C" void kernel_launch(void* const* d_in, const int* in_sizes, int n_in,
                              void* d_out, int out_size, void* d_ws, size_t ws_size,
                              hipStream_t stream) {
  const float* x    = (const float*)d_in[0];
  const float* y    = (const float*)d_in[1];
  const float* W    = (const float*)d_in[2];
  const float* bias = (const float*)d_in[3];
  float* out = (float*)d_out;

  // Workspace: A (16384x1024 bf16 = 32 MB) + Wbf16 (2 MB)
  __hip_bfloat16* Abuf = (__hip_bfloat16*)d_ws;
  __hip_bfloat16* Wbuf = (__hip_bfloat16*)((char*)d_ws + (size_t)16384 * 1024 * 2);

  attn_kernel<<<4096, 256, 0, stream>>>(x, y, Abuf, W, Wbuf);
  gemm_wp<<<512, 512, 0, stream>>>(Abuf, Wbuf, bias, out);
}

// Round 12
// 76.729 us; speedup vs baseline: 1.3535x; 1.0614x over previous
//
#include <hip/hip_runtime.h>
#include <hip/hip_bf16.h>
#include <stdint.h>

// Problem constants: B=4, N=4096, C=1024, H=16, d=64
typedef __attribute__((ext_vector_type(8))) short bf16x8;
typedef __attribute__((ext_vector_type(4))) short bf16x4;
typedef __attribute__((ext_vector_type(4))) float f32x4;
typedef __attribute__((ext_vector_type(4))) int   i32x4;

static __device__ __forceinline__ short f2bs(float f) {
  __hip_bfloat16 h = __float2bfloat16(f);
  return __builtin_bit_cast(short, h);
}

__device__ __forceinline__ void gload_lds16(const void* g, void* l) {
  auto* gp = reinterpret_cast<__attribute__((address_space(1))) uint32_t*>((uintptr_t)g);
  auto* lp = reinterpret_cast<__attribute__((address_space(3))) uint32_t*>((uintptr_t)l);
  __builtin_amdgcn_global_load_lds(gp, lp, 16, 0, 0);
}

// ---------------------------------------------------------------------------
// Kernel 1: per-token head-mix attention + fused W fp32->bf16 (unchanged).
// ---------------------------------------------------------------------------
__global__ __launch_bounds__(256) void attn_kernel(
    const float* __restrict__ x, const float* __restrict__ y,
    __hip_bfloat16* __restrict__ A,
    const float* __restrict__ W, __hip_bfloat16* __restrict__ Wb)
{
  if (blockIdx.x < 1024) {
    const int i = (blockIdx.x * 256 + threadIdx.x) * 4;
    const float4 v = *(const float4*)(W + i);
    Wb[i + 0] = __float2bfloat16(v.x);
    Wb[i + 1] = __float2bfloat16(v.y);
    Wb[i + 2] = __float2bfloat16(v.z);
    Wb[i + 3] = __float2bfloat16(v.w);
  }

  const int wid  = threadIdx.x >> 6;
  const int lane = threadIdx.x & 63;
  const int tok  = blockIdx.x * 4 + wid;        // 0..16383
  const int b    = tok >> 12;
  const int n    = tok & 4095;

  const float* xr = x + (size_t)tok * 1024;
  const float* yr = y + (size_t)tok * 1024;

  const int c  = lane & 15;
  const int qq = lane >> 4;

  const int fbase = c * 64 + qq * 8;
  bf16x8 yf[2], xf[2];
  #pragma unroll
  for (int kk = 0; kk < 2; ++kk) {
    const float4 a0 = *(const float4*)(yr + fbase + kk * 32);
    const float4 a1 = *(const float4*)(yr + fbase + kk * 32 + 4);
    const float4 b0 = *(const float4*)(xr + fbase + kk * 32);
    const float4 b1 = *(const float4*)(xr + fbase + kk * 32 + 4);
    yf[kk] = bf16x8{f2bs(a0.x), f2bs(a0.y), f2bs(a0.z), f2bs(a0.w),
                    f2bs(a1.x), f2bs(a1.y), f2bs(a1.z), f2bs(a1.w)};
    xf[kk] = bf16x8{f2bs(b0.x), f2bs(b0.y), f2bs(b0.z), f2bs(b0.w),
                    f2bs(b1.x), f2bs(b1.y), f2bs(b1.z), f2bs(b1.w)};
  }

  f32x4 acc = {0.f, 0.f, 0.f, 0.f};
  acc = __builtin_amdgcn_mfma_f32_16x16x32_bf16(yf[0], xf[0], acc, 0, 0, 0);
  acc = __builtin_amdgcn_mfma_f32_16x16x32_bf16(yf[1], xf[1], acc, 0, 0, 0);

  float sc[4];
  #pragma unroll
  for (int r = 0; r < 4; ++r) sc[r] = acc[r] * 0.125f;
  float mx = fmaxf(fmaxf(sc[0], sc[1]), fmaxf(sc[2], sc[3]));
  mx = fmaxf(mx, __shfl_xor(mx, 16));
  mx = fmaxf(mx, __shfl_xor(mx, 32));
  float e[4];
  #pragma unroll
  for (int r = 0; r < 4; ++r) e[r] = __expf(sc[r] - mx);
  float sm = (e[0] + e[1]) + (e[2] + e[3]);
  sm += __shfl_xor(sm, 16);
  sm += __shfl_xor(sm, 32);
  const float inv = 1.0f / sm;
  float p[4];
  #pragma unroll
  for (int r = 0; r < 4; ++r) p[r] = e[r] * inv;

  f32x4 o[4];
  #pragma unroll
  for (int q = 0; q < 4; ++q) o[q] = f32x4{0.f, 0.f, 0.f, 0.f};

#if __has_builtin(__builtin_amdgcn_mfma_f32_16x16x16bf16_1k)
  const bf16x4 pa = {f2bs(p[0]), f2bs(p[1]), f2bs(p[2]), f2bs(p[3])};
  #pragma unroll
  for (int q = 0; q < 4; ++q) {
    bf16x4 bq;
    #pragma unroll
    for (int j = 0; j < 4; ++j)
      bq[j] = f2bs(yr[(qq * 4 + j) * 64 + q * 16 + c]);
    o[q] = __builtin_amdgcn_mfma_f32_16x16x16bf16_1k(pa, bq, o[q], 0, 0, 0);
  }
#else
  const int u0 = ((int)(unsigned short)f2bs(p[1]) << 16) | (unsigned short)f2bs(p[0]);
  const int u1 = ((int)(unsigned short)f2bs(p[3]) << 16) | (unsigned short)f2bs(p[2]);
  const int s0 = c + 32 * qq;
  int a0 = __shfl(u0, s0), a1 = __shfl(u1, s0);
  int a2 = __shfl(u0, s0 + 16), a3 = __shfl(u1, s0 + 16);
  const bool valid = (qq < 2);
  if (!valid) { a0 = 0; a1 = 0; a2 = 0; a3 = 0; }
  const bf16x8 a8 = __builtin_bit_cast(bf16x8, i32x4{a0, a1, a2, a3});
  #pragma unroll
  for (int q = 0; q < 4; ++q) {
    bf16x8 b8;
    #pragma unroll
    for (int j = 0; j < 8; ++j) {
      const int g = (qq * 8 + j) & 15;
      const float v = yr[g * 64 + q * 16 + c];
      b8[j] = valid ? f2bs(v) : (short)0;
    }
    o[q] = __builtin_amdgcn_mfma_f32_16x16x32_bf16(a8, b8, o[q], 0, 0, 0);
  }
#endif

  const size_t base = ((size_t)b * 4096 + (n >> 4)) * 1024 + ((n & 15) << 6) + c;
  #pragma unroll
  for (int q = 0; q < 4; ++q)
    #pragma unroll
    for (int r = 0; r < 4; ++r) {
      const int h = qq * 4 + r;
      A[base + (size_t)h * 262144 + q * 16] = __float2bfloat16(o[q][r]);
    }
}

// ---------------------------------------------------------------------------
// Kernel 2: literal m97-structure GEMM  out[M,Nn] = A[M,K]*Bw[Nn,K]^T + bias.
// 128x128 tile, BK=32, 4 waves (2x2, wave 64x64), SINGLE-buffered 16 KB LDS,
// plain __syncthreads (compiler-managed waitcnt), no inline asm. The per-step
// vmcnt drain is hidden by 3 independent blocks/CU drifting out of phase
// (m114 implicit overlap — the measured-912TF recipe). Conflicts-0 swizzle,
// bijective XCD-chunked grid of 1024 blocks.
// ---------------------------------------------------------------------------
__global__ __launch_bounds__(256, 3) void gemm_m97(
    const __hip_bfloat16* __restrict__ A,   // [M=16384, K=1024] bf16
    const __hip_bfloat16* __restrict__ Bw,  // [Nn=1024, K=1024] bf16 (= W^T)
    const float* __restrict__ bias,         // [Nn]
    float* __restrict__ C)                  // [M, Nn] fp32
{
  __shared__ char ldsA[8192];               // [128 rows][64B], swizzled
  __shared__ char ldsB[8192];

  const int tid  = threadIdx.x;             // 0..255
  const int lane = tid & 63;
  const int wid  = tid >> 6;                // 4 waves: 2M x 2N
  const int wr   = wid >> 1;                // 0..1 (64 rows)
  const int wcN  = wid & 1;                 // 0..1 (64 cols)

  // bijective XCD chunking: 1024 blocks = 8 XCDs x 128 contiguous tiles
  const int bid = blockIdx.x;
  const int nb  = (bid & 7) * 128 + (bid >> 3);
  const int mBase = (nb >> 3) * 128;        // 128 M-tiles
  const int nBase = (nb & 7) * 128;         // 8 N-tiles

  // staging: linear LDS dest, pre-swizzled global source
  // thread t -> row t>>2 (0..63 per issue band), phys slot t&3 (16B)
  // swizzle involution: slot ^= (row>>1)&3  (band rows are +64 -> invariant)
  const int srow = tid >> 2;
  const int lcb  = (((tid & 3) ^ ((srow >> 1) & 3)) << 4);
  const char* aS0 = (const char*)A  + (size_t)(mBase + srow)      * 2048 + lcb;
  const char* aS1 = (const char*)A  + (size_t)(mBase + 64 + srow) * 2048 + lcb;
  const char* bS0 = (const char*)Bw + (size_t)(nBase + srow)      * 2048 + lcb;
  const char* bS1 = (const char*)Bw + (size_t)(nBase + 64 + srow) * 2048 + lcb;
  char* aD = ldsA + tid * 16;
  char* bD = ldsB + tid * 16;

  // ds_read: row R, k-quad kq -> byte R*64 + (kq ^ ((R>>1)&3))*16
  // (R = w*64 + m*16 + fr -> (R>>1)&3 == (fr>>1)&3, bases are multiples of 8)
  const int fr = lane & 15;
  const int kq = lane >> 4;
  const int ofk  = ((kq ^ ((fr >> 1) & 3)) << 4);
  const int aOff = (wr  * 64 + fr) * 64 + ofk;
  const int bOff = (wcN * 64 + fr) * 64 + ofk;

  f32x4 acc[4][4];
  #pragma unroll
  for (int m = 0; m < 4; ++m)
    #pragma unroll
    for (int n = 0; n < 4; ++n) acc[m][n] = f32x4{0.f, 0.f, 0.f, 0.f};

  for (int ko = 0; ko < 2048; ko += 64) {   // 32 K-steps (64B each along K)
    gload_lds16(aS0 + ko, aD);
    gload_lds16(aS1 + ko, aD + 4096);
    gload_lds16(bS0 + ko, bD);
    gload_lds16(bS1 + ko, bD + 4096);
    __syncthreads();                        // drains vmcnt -> tile visible

    bf16x8 Af[4], Bf[4];
    #pragma unroll
    for (int n = 0; n < 4; ++n) Bf[n] = *(const bf16x8*)(ldsB + bOff + n * 1024);
    #pragma unroll
    for (int m = 0; m < 4; ++m) Af[m] = *(const bf16x8*)(ldsA + aOff + m * 1024);

    #pragma unroll
    for (int m = 0; m < 4; ++m)
      #pragma unroll
      for (int n = 0; n < 4; ++n)
        acc[m][n] = __builtin_amdgcn_mfma_f32_16x16x32_bf16(Af[m], Bf[n], acc[m][n], 0, 0, 0);
    __syncthreads();                        // reads done before next stage
  }

  // epilogue: C/D layout col=lane&15, row=(lane>>4)*4+reg
  #pragma unroll
  for (int n = 0; n < 4; ++n) {
    const int col = nBase + wcN * 64 + n * 16 + fr;
    const float bv = bias[col];
    #pragma unroll
    for (int m = 0; m < 4; ++m) {
      const int row0 = mBase + wr * 64 + m * 16 + kq * 4;
      #pragma unroll
      for (int r = 0; r < 4; ++r)
        C[(size_t)(row0 + r) * 1024 + col] = acc[m][n][r] + bv;
    }
  }
}

extern "C" void kernel_launch(void* const* d_in, const int* in_sizes, int n_in,
                              void* d_out, int out_size, void* d_ws, size_t ws_size,
                              hipStream_t stream) {
  const float* x    = (const float*)d_in[0];
  const float* y    = (const float*)d_in[1];
  const float* W    = (const float*)d_in[2];
  const float* bias = (const float*)d_in[3];
  float* out = (float*)d_out;

  // Workspace: A (16384x1024 bf16 = 32 MB) + Wbf16 (2 MB)
  __hip_bfloat16* Abuf = (__hip_bfloat16*)d_ws;
  __hip_bfloat16* Wbuf = (__hip_bfloat16*)((char*)d_ws + (size_t)16384 * 1024 * 2);

  attn_kernel<<<4096, 256, 0, stream>>>(x, y, Abuf, W, Wbuf);
  gemm_m97<<<1024, 256, 0, stream>>>(Abuf, Wbuf, bias, out);
}